// Round 1
// baseline (195.826 us; speedup 1.0000x reference)
//
#include <hip/hip_runtime.h>
#include <hip/hip_bf16.h>

typedef __attribute__((ext_vector_type(8))) short bf16x8;
typedef __attribute__((ext_vector_type(4))) float f32x4;

#define LDSG(g, l) __builtin_amdgcn_global_load_lds(                      \
    (const __attribute__((address_space(1))) void*)(g),                   \
    (__attribute__((address_space(3))) void*)(l), 16, 0, 0)

// ---------------- kernel 1: fp32 -> bf16 convert (hidden + Wq|Wk|Wv) --------
__global__ __launch_bounds__(256) void cvt_kernel(
    const float* __restrict__ hs,
    const float* __restrict__ wq, const float* __restrict__ wk,
    const float* __restrict__ wv,
    __hip_bfloat16* __restrict__ hbf, __hip_bfloat16* __restrict__ wbf)
{
  const int NH = (4 * 1024 * 1024) / 4;   // hidden quads
  const int NW = (1024 * 1024) / 4;       // per-W quads
  int i = blockIdx.x * 256 + threadIdx.x; // exact grid: NH + 3*NW quads
  float4 v;
  __hip_bfloat16* dst;
  if (i < NH) {
    v = ((const float4*)hs)[i];
    dst = hbf + (size_t)i * 4;
  } else {
    int j = i - NH;
    int which = j / NW, r = j - which * NW;
    const float* src = which == 0 ? wq : (which == 1 ? wk : wv);
    v = ((const float4*)src)[r];
    dst = wbf + (size_t)j * 4;
  }
  union { ushort4 u; __hip_bfloat16 b[4]; } o;
  o.b[0] = __float2bfloat16(v.x);
  o.b[1] = __float2bfloat16(v.y);
  o.b[2] = __float2bfloat16(v.z);
  o.b[3] = __float2bfloat16(v.w);
  *((ushort4*)dst) = o.u;
}

// ---------------- kernel 2: QKV GEMM  C[4096][3072] = A[4096][1024] @ W^T ---
// 128x128 tile, BK=64, 4 waves (2x2), each wave 64x64 (4x4 frags of 16x16).
// LDS XOR-swizzle (chunk ^= row&7, 16B chunks) applied by pre-swizzling the
// global source address (global_load_lds dest must stay linear).
__global__ __launch_bounds__(256) void qkv_gemm(
    const __hip_bfloat16* __restrict__ A,  // [4096][1024]
    const __hip_bfloat16* __restrict__ W,  // [3072][1024] (q,k,v stacked)
    const float* __restrict__ bq, const float* __restrict__ bk,
    const float* __restrict__ bv,
    __hip_bfloat16* __restrict__ qo, __hip_bfloat16* __restrict__ ko,
    __hip_bfloat16* __restrict__ vo)       // each [B=4][H=16][S=1024][D=64]
{
  const int K = 1024;
  __shared__ __hip_bfloat16 As[128 * 64];
  __shared__ __hip_bfloat16 Bs[128 * 64];
  const int bid = blockIdx.x;
  const int bm = bid & 31, bn = bid >> 5;
  const int m0 = bm * 128, n0 = bn * 128;
  const int tid = threadIdx.x, wid = tid >> 6, lane = tid & 63;
  const int wm = wid >> 1, wn = wid & 1;

  f32x4 acc[4][4] = {};

  const int srow = lane >> 3;              // 0..7 (row within 8-row group)
  const int schunk = (lane & 7) ^ srow;    // swizzled 16B-chunk in row

  for (int k0 = 0; k0 < K; k0 += 64) {
#pragma unroll
    for (int p = 0; p < 4; ++p) {
      int r = (wid * 4 + p) * 8 + srow;    // 0..127
      LDSG(&A[(size_t)(m0 + r) * K + k0 + schunk * 8], &As[(wid * 4 + p) * 512]);
      LDSG(&W[(size_t)(n0 + r) * K + k0 + schunk * 8], &Bs[(wid * 4 + p) * 512]);
    }
    __syncthreads();
#pragma unroll
    for (int ks = 0; ks < 2; ++ks) {
      bf16x8 af[4], bfr[4];
#pragma unroll
      for (int mi = 0; mi < 4; ++mi) {
        int row = wm * 64 + mi * 16 + (lane & 15);
        int slot = (ks * 4 + (lane >> 4)) ^ (lane & 7); // row&7 == lane&7
        af[mi] = *(const bf16x8*)((const char*)As + row * 128 + slot * 16);
      }
#pragma unroll
      for (int ni = 0; ni < 4; ++ni) {
        int row = wn * 64 + ni * 16 + (lane & 15);
        int slot = (ks * 4 + (lane >> 4)) ^ (lane & 7);
        bfr[ni] = *(const bf16x8*)((const char*)Bs + row * 128 + slot * 16);
      }
#pragma unroll
      for (int mi = 0; mi < 4; ++mi)
#pragma unroll
        for (int ni = 0; ni < 4; ++ni)
          acc[mi][ni] = __builtin_amdgcn_mfma_f32_16x16x32_bf16(
              af[mi], bfr[ni], acc[mi][ni], 0, 0, 0);
    }
    __syncthreads();
  }

  // epilogue: bias add; q additionally scaled by 1/sqrt(D)=0.125; write
  // bf16 to [b][h][s][d].  C/D layout: col = lane&15, row = (lane>>4)*4+j.
#pragma unroll
  for (int ni = 0; ni < 4; ++ni) {
    int n = n0 + wn * 64 + ni * 16 + (lane & 15);
    int which = n >> 10;         // 0=q 1=k 2=v (uniform per ni)
    int h = (n >> 6) & 15;
    int d = n & 63;
    const float* bias = which == 0 ? bq : (which == 1 ? bk : bv);
    float bval = bias[n & 1023];
    __hip_bfloat16* dst = which == 0 ? qo : (which == 1 ? ko : vo);
    float scale = (which == 0) ? 0.125f : 1.0f;
#pragma unroll
    for (int mi = 0; mi < 4; ++mi) {
#pragma unroll
      for (int j = 0; j < 4; ++j) {
        int m = m0 + wm * 64 + mi * 16 + (lane >> 4) * 4 + j;
        int b = m >> 10, s = m & 1023;
        float val = (acc[mi][ni][j] + bval) * scale;
        dst[(((size_t)(b * 16 + h) << 10) + s) * 64 + d] = __float2bfloat16(val);
      }
    }
  }
}

// ---------------- kernel 3: flash attention with rel-bias streaming ---------
// grid: 1024 blocks = 64 (b,h) x 16 q-tiles of 64 rows. 4 waves, wave w owns
// q rows [qt*64 + w*16, +16). Online softmax; per-row stats live in the
// 16-lane group (4 rows per lane via acc reg j).
__global__ __launch_bounds__(256) void attn_kernel(
    const __hip_bfloat16* __restrict__ q, const __hip_bfloat16* __restrict__ k,
    const __hip_bfloat16* __restrict__ v,
    const float* __restrict__ rel1, const float* __restrict__ rel2,
    const float* __restrict__ mask, float* __restrict__ out)
{
  __shared__ __hip_bfloat16 Ks[64 * 64];
  __shared__ __hip_bfloat16 Vs[64 * 64];
  __shared__ __hip_bfloat16 Ps[4][16 * 64];

  const int bid = blockIdx.x;
  const int bh = bid & 63, qt = bid >> 6;   // same-bh blocks share an XCD
  const int b = bh >> 4, h = bh & 15;
  const int tid = threadIdx.x, wid = tid >> 6, lane = tid & 63;

  const size_t kvbase = (size_t)bh << 16;   // bh * 1024 * 64 elements

  // Q fragments (A-operand: row = lane&15, k = ks*32 + (lane>>4)*8 .. +8)
  const int qrow = qt * 64 + wid * 16 + (lane & 15);
  bf16x8 qf[2];
  qf[0] = *(const bf16x8*)&q[kvbase + (size_t)qrow * 64 + (lane >> 4) * 8];
  qf[1] = *(const bf16x8*)&q[kvbase + (size_t)qrow * 64 + 32 + (lane >> 4) * 8];

  f32x4 accO[4] = {};
  float mrun[4], lrun[4];
#pragma unroll
  for (int j = 0; j < 4; ++j) { mrun[j] = -1e30f; lrun[j] = 0.f; }

  const int srow = lane >> 3;
  const int schunk = (lane & 7) ^ srow;
  const float* relp1 = rel1 + ((size_t)bh << 20);
  const float* relp2 = rel2 + ((size_t)bh << 20);
  const int qrow_c = qt * 64 + wid * 16 + (lane >> 4) * 4; // acc row base

  for (int kt = 0; kt < 16; ++kt) {
    const int kb = kt * 64;

    // rel bias loads straight into accumulator layout (fp32 dwords; one wave
    // instruction covers 4 full 64B lines)
    float r1[4][4], r2[4][4];
#pragma unroll
    for (int ct = 0; ct < 4; ++ct)
#pragma unroll
      for (int j = 0; j < 4; ++j) {
        size_t off = (size_t)(qrow_c + j) * 1024 + kb + ct * 16 + (lane & 15);
        r1[ct][j] = relp1[off];
        r2[ct][j] = relp2[off];
      }

    // stage K (swizzled) and V (linear) tiles
#pragma unroll
    for (int p = 0; p < 2; ++p) {
      int r = (wid * 2 + p) * 8 + srow;
      LDSG(&k[kvbase + (size_t)(kb + r) * 64 + schunk * 8], &Ks[(wid * 2 + p) * 512]);
      LDSG(&v[kvbase + (size_t)(kb + r) * 64 + (lane & 7) * 8], &Vs[(wid * 2 + p) * 512]);
    }
    __syncthreads();

    // QK^T (q pre-scaled by 1/sqrt(D))
    f32x4 s4[4] = {};
#pragma unroll
    for (int ks = 0; ks < 2; ++ks) {
#pragma unroll
      for (int ct = 0; ct < 4; ++ct) {
        int row = ct * 16 + (lane & 15);
        int slot = (ks * 4 + (lane >> 4)) ^ (lane & 7);
        bf16x8 kf = *(const bf16x8*)((const char*)Ks + row * 128 + slot * 16);
        s4[ct] = __builtin_amdgcn_mfma_f32_16x16x32_bf16(qf[ks], kf, s4[ct], 0, 0, 0);
      }
    }

    // scores = qk + 0.125*(rel1+rel2) + mask ; tile row-max
    float p[4][4], mt[4];
#pragma unroll
    for (int j = 0; j < 4; ++j) mt[j] = -1e30f;
#pragma unroll
    for (int ct = 0; ct < 4; ++ct) {
      float mval = mask[(size_t)b * 1024 + kb + ct * 16 + (lane & 15)];
#pragma unroll
      for (int j = 0; j < 4; ++j) {
        float sv = s4[ct][j] + 0.125f * (r1[ct][j] + r2[ct][j]) + mval;
        p[ct][j] = sv;
        mt[j] = fmaxf(mt[j], sv);
      }
    }
#pragma unroll
    for (int off = 1; off < 16; off <<= 1)
#pragma unroll
      for (int j = 0; j < 4; ++j)
        mt[j] = fmaxf(mt[j], __shfl_xor(mt[j], off, 64));

    float sc[4], lsum[4];
#pragma unroll
    for (int j = 0; j < 4; ++j) {
      float mnew = fmaxf(mrun[j], mt[j]);
      sc[j] = __expf(mrun[j] - mnew);
      mrun[j] = mnew;
      lsum[j] = 0.f;
    }
#pragma unroll
    for (int ct = 0; ct < 4; ++ct)
#pragma unroll
      for (int j = 0; j < 4; ++j) {
        float e = __expf(p[ct][j] - mrun[j]);
        p[ct][j] = e;
        lsum[j] += e;
      }
#pragma unroll
    for (int off = 1; off < 16; off <<= 1)
#pragma unroll
      for (int j = 0; j < 4; ++j) lsum[j] += __shfl_xor(lsum[j], off, 64);
#pragma unroll
    for (int j = 0; j < 4; ++j) lrun[j] = lrun[j] * sc[j] + lsum[j];
#pragma unroll
    for (int dt = 0; dt < 4; ++dt)
#pragma unroll
      for (int j = 0; j < 4; ++j) accO[dt][j] *= sc[j];

    // P -> LDS (bf16, wave-private), read back in A-fragment layout
    __hip_bfloat16* Pw = &Ps[wid][0];
#pragma unroll
    for (int ct = 0; ct < 4; ++ct)
#pragma unroll
      for (int j = 0; j < 4; ++j)
        Pw[((lane >> 4) * 4 + j) * 64 + ct * 16 + (lane & 15)] =
            __float2bfloat16(p[ct][j]);
    bf16x8 pa[2];
    pa[0] = *(const bf16x8*)&Pw[(lane & 15) * 64 + (lane >> 4) * 8];
    pa[1] = *(const bf16x8*)&Pw[(lane & 15) * 64 + 32 + (lane >> 4) * 8];

    // PV: B-operand gathered from Vs ([k][d] linear) by scalar reads
#pragma unroll
    for (int ks = 0; ks < 2; ++ks) {
#pragma unroll
      for (int dt = 0; dt < 4; ++dt) {
        bf16x8 vf;
#pragma unroll
        for (int jj = 0; jj < 8; ++jj) {
          int krow = ks * 32 + (lane >> 4) * 8 + jj;
          ((short*)&vf)[jj] =
              *(const short*)&Vs[krow * 64 + dt * 16 + (lane & 15)];
        }
        accO[dt] = __builtin_amdgcn_mfma_f32_16x16x32_bf16(pa[ks], vf, accO[dt], 0, 0, 0);
      }
    }
    __syncthreads();
  }

  // epilogue: out[b][s][h*64+d] = accO / lrun
#pragma unroll
  for (int dt = 0; dt < 4; ++dt)
#pragma unroll
    for (int j = 0; j < 4; ++j) {
      int s = qrow_c + j;
      out[((size_t)(b * 1024 + s)) * 1024 + h * 64 + dt * 16 + (lane & 15)] =
          accO[dt][j] / lrun[j];
    }
}

// ---------------------------------------------------------------------------
extern "C" void kernel_launch(void* const* d_in, const int* in_sizes, int n_in,
                              void* d_out, int out_size, void* d_ws,
                              size_t ws_size, hipStream_t stream) {
  const float* hs   = (const float*)d_in[0];
  const float* mask = (const float*)d_in[1];
  const float* rel1 = (const float*)d_in[2];
  const float* rel2 = (const float*)d_in[3];
  const float* Wq   = (const float*)d_in[4];
  const float* bq   = (const float*)d_in[5];
  const float* Wk   = (const float*)d_in[6];
  const float* bk   = (const float*)d_in[7];
  const float* Wv   = (const float*)d_in[8];
  const float* bv   = (const float*)d_in[9];

  char* ws = (char*)d_ws;
  __hip_bfloat16* hbf = (__hip_bfloat16*)(ws);              // 8 MB
  __hip_bfloat16* wbf = (__hip_bfloat16*)(ws + 8388608);    // 6 MB
  __hip_bfloat16* qb  = (__hip_bfloat16*)(ws + 14680064);   // 8 MB
  __hip_bfloat16* kb  = (__hip_bfloat16*)(ws + 23068672);   // 8 MB
  __hip_bfloat16* vb  = (__hip_bfloat16*)(ws + 31457280);   // 8 MB (total 38 MB)

  cvt_kernel<<<7168, 256, 0, stream>>>(hs, Wq, Wk, Wv, hbf, wbf);
  qkv_gemm<<<768, 256, 0, stream>>>(hbf, wbf, bq, bk, bv, qb, kb, vb);
  attn_kernel<<<1024, 256, 0, stream>>>(qb, kb, vb, rel1, rel2, mask,
                                        (float*)d_out);
}